// Round 5
// baseline (845.302 us; speedup 1.0000x reference)
//
#include <hip/hip_runtime.h>

#define BLOCK 256
#define NNODE 1024
#define NH    992
#define NE    1984
#define NSORT 2048
#define LMAX  12
#define CHUNK 64
#define NPASS (NE / CHUNK)

typedef unsigned long long ull;

__device__ __forceinline__ void edge_nodes(int e, int& a, int& b) {
    if (e < NH) {                 // horizontal: (r,c)-(r,c+1), e = r*31+c
        int r = e / 31;
        int c = e - r * 31;
        a = (r << 5) + c;
        b = a + 1;
    } else {                      // vertical: (r,c)-(r+1,c), e-992 = r*32+c
        a = e - NH;
        b = a + 32;
    }
}

// Parallel-safe find with full path compression. Concurrent lanes may race on
// parent writes, but every written value is an ancestor of the node in the
// (static during this phase) forest, so roots are preserved.
__device__ __forceinline__ int find_par(unsigned short* par, int x) {
    volatile unsigned short* vp = par;
    int r = x;
    int p = vp[r];
    while (p != r) { r = p; p = vp[r]; }
    int c = x;
    while (c != r) { const int nxt = vp[c]; vp[c] = (unsigned short)r; c = nxt; }
    return r;
}

// dot product of 4 packed u16 lanes
__device__ __forceinline__ int dot16x4(ull a, ull b) {
    int s  = (int)(a & 0xFFFFu)         * (int)(b & 0xFFFFu);
    s     += (int)((a >> 16) & 0xFFFFu) * (int)((b >> 16) & 0xFFFFu);
    s     += (int)((a >> 32) & 0xFFFFu) * (int)((b >> 32) & 0xFFFFu);
    s     += (int)((a >> 48) & 0xFFFFu) * (int)((b >> 48) & 0xFFFFu);
    return s;
}

// bitonic compare-exchange on (key, idx), ascending iff up
__device__ __forceinline__ void cswap(unsigned int& ka, unsigned short& ia,
                                      unsigned int& kb, unsigned short& ib, bool up) {
    const bool gt = (ka > kb) || (ka == kb && ia > ib);
    if (gt == up) {
        const unsigned int  tk = ka; ka = kb; kb = tk;
        const unsigned short ti = ia; ia = ib; ib = ti;
    }
}

__global__ __launch_bounds__(BLOCK) void conn_kernel(const float* __restrict__ pred,
                                                     const float* __restrict__ tgt,
                                                     double* __restrict__ acc_ws,
                                                     int B) {
    __shared__ alignas(16) float          sh_p[NNODE];
    __shared__ alignas(16) float          sh_t[NNODE];
    __shared__ alignas(16) unsigned int   sh_key[NSORT];   // sort keys; later reused as w bits
    __shared__ alignas(16) unsigned short sh_idx[NSORT];   // sort payload (edge ids); early: dilate scratch
    __shared__ unsigned short sh_parent[NNODE];       // CC labels, then UF parent
    __shared__ unsigned int   sh_szto[NNODE];         // lo16 = UF size, hi16 = tot; early: root->label map
    __shared__ ull            sh_cnt64[NNODE * 3];    // 12 packed u16 label counts per node
    __shared__ unsigned char  sh_seg[NNODE];          // early: mask / fg
    __shared__ int            sh_flag;
    __shared__ int            sh_L;
    __shared__ float          sh_sn;
    __shared__ double         sh_red[4];

    const int tid = threadIdx.x;
    int wg = blockIdx.x;
    // XCD pair-swizzle: dispatch round-robins XCD = blockIdx % 8. Take sign
    // from bit 3 so the two sign-blocks (identical projection reads) land on
    // the SAME XCD and share L2. Grid = 192*B is divisible by 16.
    const int sign = (wg >> 3) & 1;                   // 0 = neg, 1 = pos
    wg = (wg & 7) | ((wg >> 4) << 3);                 // compact remaining bits
    const int b    = wg % B;  wg /= B;
    const int win  = wg & 3;  wg >>= 2;
    const int item = wg;                              // 0..23
    const int axis_id = item % 3;                     // 0:reduce z(H), 1:reduce y(W), 2:reduce x(D)
    const int cube = item / 3;
    const int ci = cube & 1;                          // x block
    const int cj = (cube >> 1) & 1;                   // y block
    const int ck = (cube >> 2) & 1;                   // z block
    const int wk = win >> 1;                          // window row block
    const int wj = win & 1;                           // window col block

    const size_t base = (size_t)b * 2097152u;

    // ---- projection mins (32x32 window of the 64x64 projection) ----
    if (axis_id == 2) {
        // reduced axis contiguous: float4 along the reduction
        for (int pix = tid; pix < NNODE; pix += BLOCK) {
            const int r = pix >> 5, c = pix & 31;
            const int R = wk * 32 + r, C = wj * 32 + c;
            const size_t idx0 = base + (size_t)(ck * 64 + R) * 16384u + (size_t)(cj * 64 + C) * 128u + (size_t)(ci * 64);
            const float4* pp = reinterpret_cast<const float4*>(pred + idx0);
            const float4* tp = reinterpret_cast<const float4*>(tgt + idx0);
            float pm = 3.4e38f, tm = 3.4e38f;
            #pragma unroll
            for (int h = 0; h < 16; ++h) {
                const float4 a = pp[h];
                const float4 t = tp[h];
                pm = fminf(pm, fminf(fminf(a.x, a.y), fminf(a.z, a.w)));
                tm = fminf(tm, fminf(fminf(t.x, t.y), fminf(t.z, t.w)));
            }
            sh_p[pix] = pm;
            sh_t[pix] = tm;
        }
    } else {
        // reduced axis strided: float4 along the window's contiguous x axis.
        // thread t owns row r = t>>3, cols c0..c0+3 with c0 = (t&7)*4.
        const int r  = tid >> 3;
        const int c0 = (tid & 7) << 2;
        const int R = wk * 32 + r, C = wj * 32 + c0;
        size_t idx0; int hstride;
        if (axis_id == 0) {
            idx0 = base + (size_t)(ck * 64) * 16384u + (size_t)(cj * 64 + R) * 128u + (size_t)(ci * 64 + C);
            hstride = 16384;
        } else {
            idx0 = base + (size_t)(ck * 64 + R) * 16384u + (size_t)(cj * 64) * 128u + (size_t)(ci * 64 + C);
            hstride = 128;
        }
        float4 pm = make_float4(3.4e38f, 3.4e38f, 3.4e38f, 3.4e38f);
        float4 tm = pm;
        #pragma unroll 8
        for (int h = 0; h < 64; ++h) {
            const float4 a  = *reinterpret_cast<const float4*>(pred + idx0);
            const float4 t4 = *reinterpret_cast<const float4*>(tgt + idx0);
            pm.x = fminf(pm.x, a.x);  pm.y = fminf(pm.y, a.y);
            pm.z = fminf(pm.z, a.z);  pm.w = fminf(pm.w, a.w);
            tm.x = fminf(tm.x, t4.x); tm.y = fminf(tm.y, t4.y);
            tm.z = fminf(tm.z, t4.z); tm.w = fminf(tm.w, t4.w);
            idx0 += (size_t)hstride;
        }
        *reinterpret_cast<float4*>(&sh_p[(r << 5) + c0]) = pm;
        *reinterpret_cast<float4*>(&sh_t[(r << 5) + c0]) = tm;
    }
    __syncthreads();

    // ---- dilate5 of (t == 0), von Neumann, zero padded, window-local ----
    unsigned char* mA = sh_seg;
    unsigned char* mB = (unsigned char*)sh_idx;
    for (int pix = tid; pix < NNODE; pix += BLOCK)
        mA[pix] = (sh_t[pix] == 0.0f) ? 1 : 0;
    __syncthreads();
    for (int it = 0; it < 5; ++it) {
        unsigned char* src = (it & 1) ? mB : mA;
        unsigned char* dst = (it & 1) ? mA : mB;
        for (int pix = tid; pix < NNODE; pix += BLOCK) {
            const int r = pix >> 5, c = pix & 31;
            unsigned char v = src[pix];
            if (r > 0)  v |= src[pix - 32];
            if (r < 31) v |= src[pix + 32];
            if (c > 0)  v |= src[pix - 1];
            if (c < 31) v |= src[pix + 1];
            dst[pix] = v;
        }
        __syncthreads();
    }
    // result in mB; fg = !mB into mA
    for (int pix = tid; pix < NNODE; pix += BLOCK)
        mA[pix] = mB[pix] ^ 1;
    __syncthreads();

    // ---- 8-connected CC labeling on fg via min-index propagation ----
    for (int pix = tid; pix < NNODE; pix += BLOCK)
        sh_parent[pix] = mA[pix] ? (unsigned short)pix : (unsigned short)0xFFFF;
    __syncthreads();
    for (;;) {
        if (tid == 0) sh_flag = 0;
        __syncthreads();
        for (int pix = tid; pix < NNODE; pix += BLOCK) {
            if (!mA[pix]) continue;
            const int r = pix >> 5, c = pix & 31;
            int m = sh_parent[pix];
            #pragma unroll
            for (int d = 0; d < 8; ++d) {
                static const int dr[8] = {-1,-1,-1, 0, 0, 1, 1, 1};
                static const int dc[8] = {-1, 0, 1,-1, 1,-1, 0, 1};
                const int rr = r + dr[d], cc = c + dc[d];
                if (rr < 0 || rr > 31 || cc < 0 || cc > 31) continue;
                const int nb = (rr << 5) + cc;
                if (mA[nb]) { int v = sh_parent[nb]; if (v < m) m = v; }
            }
            while ((int)sh_parent[m] < m) m = sh_parent[m];
            if (m < (int)sh_parent[pix]) { sh_parent[pix] = (unsigned short)m; sh_flag = 1; }
        }
        __syncthreads();
        const int f = sh_flag;
        __syncthreads();
        if (f == 0) break;
    }

    // ---- compact labels (equality is all that matters) ----
    if (tid == 0) sh_L = 0;
    __syncthreads();
    for (int pix = tid; pix < NNODE; pix += BLOCK) {
        if (mA[pix] && (int)sh_parent[pix] == pix) {
            const int id = atomicAdd(&sh_L, 1);
            sh_szto[pix] = (unsigned int)(id + 1);    // root -> label map
        }
    }
    __syncthreads();
    for (int pix = tid; pix < NNODE; pix += BLOCK) {
        unsigned char s = 0;
        if (mA[pix]) {
            int lab = (int)sh_szto[sh_parent[pix]];
            if (lab > 255) lab = 255;
            s = (unsigned char)lab;
        }
        sh_seg[pix] = s;   // overwrites mA (fg) — per-pixel read precedes write
    }
    __syncthreads();

    // ---- union-find init (packed: szto = size | tot<<16; cnt = 3x u64 of 4x u16) ----
    for (int pix = tid; pix < NNODE; pix += BLOCK) {
        sh_parent[pix] = (unsigned short)pix;
        const int s = sh_seg[pix];
        const unsigned int tot = (s > 0 && s <= LMAX) ? 1u : 0u;
        sh_szto[pix] = 1u | (tot << 16);
        ull c0 = 0, c1 = 0, c2 = 0;
        if (s >= 1 && s <= LMAX) {
            const ull bit = 1ull << (((s - 1) & 3) * 16);
            const int q = (s - 1) >> 2;
            if (q == 0) c0 = bit; else if (q == 1) c1 = bit; else c2 = bit;
        }
        sh_cnt64[pix * 3 + 0] = c0;
        sh_cnt64[pix * 3 + 1] = c1;
        sh_cnt64[pix * 3 + 2] = c2;
    }
    __syncthreads();   // sh_p/sh_t stable; register build below reads them

    // ---- build sort keys DIRECTLY in registers (thread t owns elements 8t..8t+7)
    //      and run the k=2,4,8 bitonic rounds in-register before first store ----
    unsigned int   K[8];
    unsigned short I[8];
    const int b8 = tid << 3;
    #pragma unroll
    for (int l = 0; l < 8; ++l) {
        const int e = b8 + l;
        if (e < NE) {
            int a, bb; edge_nodes(e, a, bb);
            float cost = sh_p[a] + sh_p[bb];
            const float g = sh_t[a] + sh_t[bb];
            if (sign == 0) { if (g > 10.0f) cost = 10.0f; }
            else           { if (g <  3.0f) cost = 0.0f;  }
            K[l] = ~__float_as_uint(cost);
            I[l] = (unsigned short)e;
        } else {
            K[l] = 0xFFFFFFFFu;
            I[l] = (unsigned short)0xFFFF;
        }
    }
    // k=2, j=1 (up by (i&2)==0)
    cswap(K[0],I[0],K[1],I[1], true );
    cswap(K[2],I[2],K[3],I[3], false);
    cswap(K[4],I[4],K[5],I[5], true );
    cswap(K[6],I[6],K[7],I[7], false);
    // k=4, j=2 (up by (i&4)==0)
    cswap(K[0],I[0],K[2],I[2], true );
    cswap(K[1],I[1],K[3],I[3], true );
    cswap(K[4],I[4],K[6],I[6], false);
    cswap(K[5],I[5],K[7],I[7], false);
    // k=4, j=1
    cswap(K[0],I[0],K[1],I[1], true );
    cswap(K[2],I[2],K[3],I[3], true );
    cswap(K[4],I[4],K[5],I[5], false);
    cswap(K[6],I[6],K[7],I[7], false);
    // k=8: up uniform per thread = ((b8 & 8) == 0)
    {
        const bool u8 = ((b8 & 8) == 0);
        cswap(K[0],I[0],K[4],I[4], u8); cswap(K[1],I[1],K[5],I[5], u8);
        cswap(K[2],I[2],K[6],I[6], u8); cswap(K[3],I[3],K[7],I[7], u8);
        cswap(K[0],I[0],K[2],I[2], u8); cswap(K[1],I[1],K[3],I[3], u8);
        cswap(K[4],I[4],K[6],I[6], u8); cswap(K[5],I[5],K[7],I[7], u8);
        cswap(K[0],I[0],K[1],I[1], u8); cswap(K[2],I[2],K[3],I[3], u8);
        cswap(K[4],I[4],K[5],I[5], u8); cswap(K[6],I[6],K[7],I[7], u8);
    }
    // store session
    {
        uint4 k0, k1, iv;
        k0.x=K[0]; k0.y=K[1]; k0.z=K[2]; k0.w=K[3];
        k1.x=K[4]; k1.y=K[5]; k1.z=K[6]; k1.w=K[7];
        iv.x=(unsigned int)I[0] | ((unsigned int)I[1]<<16);
        iv.y=(unsigned int)I[2] | ((unsigned int)I[3]<<16);
        iv.z=(unsigned int)I[4] | ((unsigned int)I[5]<<16);
        iv.w=(unsigned int)I[6] | ((unsigned int)I[7]<<16);
        *reinterpret_cast<uint4*>(&sh_key[b8])     = k0;
        *reinterpret_cast<uint4*>(&sh_key[b8 + 4]) = k1;
        *reinterpret_cast<uint4*>(&sh_idx[b8])     = iv;
    }
    __syncthreads();

    // ---- bitonic rounds k=16..2048: j>=8 via LDS (pair-indexed, all threads
    //      active), j=4,2,1 tail in registers ----
    for (int k = 16; k <= NSORT; k <<= 1) {
        for (int j = k >> 1; j >= 8; j >>= 1) {
            for (int p = tid; p < (NSORT >> 1); p += BLOCK) {
                const int i   = ((p & ~(j - 1)) << 1) | (p & (j - 1));
                const int ixj = i | j;
                const unsigned int ka = sh_key[i], kb = sh_key[ixj];
                const unsigned short ia = sh_idx[i], ib = sh_idx[ixj];
                const bool gt = (ka > kb) || (ka == kb && ia > ib);
                const bool up = ((i & k) == 0);
                if (gt == up) {
                    sh_key[i] = kb; sh_key[ixj] = ka;
                    sh_idx[i] = ib; sh_idx[ixj] = ia;
                }
            }
            __syncthreads();
        }
        // register tail: j = 4, 2, 1 (direction uniform within the 8-block)
        {
            const uint4 k0 = *reinterpret_cast<const uint4*>(&sh_key[b8]);
            const uint4 k1 = *reinterpret_cast<const uint4*>(&sh_key[b8 + 4]);
            const uint4 iv = *reinterpret_cast<const uint4*>(&sh_idx[b8]);
            K[0]=k0.x; K[1]=k0.y; K[2]=k0.z; K[3]=k0.w;
            K[4]=k1.x; K[5]=k1.y; K[6]=k1.z; K[7]=k1.w;
            I[0]=(unsigned short)(iv.x); I[1]=(unsigned short)(iv.x>>16);
            I[2]=(unsigned short)(iv.y); I[3]=(unsigned short)(iv.y>>16);
            I[4]=(unsigned short)(iv.z); I[5]=(unsigned short)(iv.z>>16);
            I[6]=(unsigned short)(iv.w); I[7]=(unsigned short)(iv.w>>16);
            const bool u8 = ((b8 & k) == 0);
            cswap(K[0],I[0],K[4],I[4], u8); cswap(K[1],I[1],K[5],I[5], u8);
            cswap(K[2],I[2],K[6],I[6], u8); cswap(K[3],I[3],K[7],I[7], u8);
            cswap(K[0],I[0],K[2],I[2], u8); cswap(K[1],I[1],K[3],I[3], u8);
            cswap(K[4],I[4],K[6],I[6], u8); cswap(K[5],I[5],K[7],I[7], u8);
            cswap(K[0],I[0],K[1],I[1], u8); cswap(K[2],I[2],K[3],I[3], u8);
            cswap(K[4],I[4],K[5],I[5], u8); cswap(K[6],I[6],K[7],I[7], u8);
            uint4 o0, o1, ov;
            o0.x=K[0]; o0.y=K[1]; o0.z=K[2]; o0.w=K[3];
            o1.x=K[4]; o1.y=K[5]; o1.z=K[6]; o1.w=K[7];
            ov.x=(unsigned int)I[0] | ((unsigned int)I[1]<<16);
            ov.y=(unsigned int)I[2] | ((unsigned int)I[3]<<16);
            ov.z=(unsigned int)I[4] | ((unsigned int)I[5]<<16);
            ov.w=(unsigned int)I[6] | ((unsigned int)I[7]<<16);
            *reinterpret_cast<uint4*>(&sh_key[b8])     = o0;
            *reinterpret_cast<uint4*>(&sh_key[b8 + 4]) = o1;
            *reinterpret_cast<uint4*>(&sh_idx[b8])     = ov;
        }
        __syncthreads();
    }

    // ---- zero edge weights (reuse key array as float bits) ----
    for (int e = tid; e < NE; e += BLOCK) sh_key[e] = 0u;   // 0.0f
    __syncthreads();

    // ---- single-wave PARALLEL-COMMIT Kruskal (wave 0, no block barriers) ----
    // Per 64-edge chunk: compute current roots per lane, build a 64x64
    // conflict matrix in registers (lanes conflict iff root-pairs intersect),
    // then commit rounds: every pending lane with no EARLIER-ordered pending
    // conflict commits ITS OWN merge in parallel (prefix-closed independent
    // set -> each commit sees exactly the serial-prefix state; disjoint merges
    // commute and weights depend only on the two components involved).
    // After each round: LDS fence (cross-lane visibility), conflict
    // propagation (lanes conflicting with a committed lane now mutually
    // conflict), root remap via 1-hop parallel find.
    if (tid < 64) {
        const int lane = tid;
        const ull below = (lane == 0) ? 0ull : (~0ull >> (64 - lane));
        for (int pass = 0; pass < NPASS; ++pass) {
            const int e = sh_idx[pass * CHUNK + lane];
            int a, bb; edge_nodes(e, a, bb);
            int ra = find_par(sh_parent, a);
            int rb = find_par(sh_parent, bb);
            ull P = __ballot(ra != rb);
            if (P == 0) continue;
            // conflict matrix row (bit j: lane j's candidate shares a root)
            ull conf = 0;
            {
                const unsigned int mypack = (unsigned int)ra | ((unsigned int)rb << 10);
                ull t = P;
                while (t) {
                    const int j = (int)__builtin_ctzll(t); t &= t - 1;
                    const unsigned int o = (unsigned int)__shfl((int)mypack, j);
                    const int ora = (int)(o & 1023u), orb = (int)((o >> 10) & 1023u);
                    if (ra == ora || ra == orb || rb == ora || rb == orb)
                        conf |= (1ull << j);
                }
            }
            while (P) {
                const bool mine = ((P >> lane) & 1ull) != 0ull;
                const bool ok = mine && ((conf & P & below) == 0ull);
                const ull S = __ballot(ok);
                if (ok) {
                    // per-lane commit: roots disjoint across committed lanes
                    const unsigned int xa = sh_szto[ra], xb = sh_szto[rb];
                    const ull a0 = sh_cnt64[ra * 3 + 0];
                    const ull a1 = sh_cnt64[ra * 3 + 1];
                    const ull a2 = sh_cnt64[ra * 3 + 2];
                    const ull b0 = sh_cnt64[rb * 3 + 0];
                    const ull b1 = sh_cnt64[rb * 3 + 1];
                    const ull b2 = sh_cnt64[rb * 3 + 2];
                    const int ta = (int)(xa >> 16), tb = (int)(xb >> 16);
                    const int same = dot16x4(a0, b0) + dot16x4(a1, b1) + dot16x4(a2, b2);
                    const int wv = sign ? same : (ta * tb - same);
                    // survivor = larger component (weight symmetric; union by size)
                    const int big = ((xa & 0xFFFFu) > (xb & 0xFFFFu));
                    const int rs = big ? ra : rb;
                    const int rl = big ? rb : ra;
                    sh_key[e] = __float_as_uint((float)wv);
                    // per-lane sums <= 1024 -> no cross-lane carry
                    sh_cnt64[rs * 3 + 0] = a0 + b0;
                    sh_cnt64[rs * 3 + 1] = a1 + b1;
                    sh_cnt64[rs * 3 + 2] = a2 + b2;
                    // size sum <= 2048, tot sum <= 2048 -> no field carry
                    sh_szto[rs] = xa + xb;
                    sh_parent[rl] = (unsigned short)rs;
                }
                // make cross-lane LDS stores visible to subsequent reads;
                // asm blocks compiler reordering, waitcnt drains the DS queue
                asm volatile("s_waitcnt lgkmcnt(0)" ::: "memory");
                __builtin_amdgcn_sched_barrier(0);
                // conflict propagation: lanes conflicting with committed j now
                // mutually conflict (their roots merged into one component)
                ull s2 = S;
                while (s2) {
                    const int j = (int)__builtin_ctzll(s2); s2 &= s2 - 1;
                    const bool withj = ((conf >> j) & 1ull) != 0ull;
                    const ull Cj = __ballot(withj);
                    if (withj) conf |= Cj;
                }
                P &= ~S;
                const bool alive = ((P >> lane) & 1ull) != 0ull;
                if (alive) {
                    ra = find_par(sh_parent, ra);
                    rb = find_par(sh_parent, rb);
                }
                P = __ballot(alive && ra != rb);
            }
        }
    }
    __syncthreads();

    // ---- normalization sum (all weights integer-valued < 2^24: exact) ----
    {
        float part = 0.0f;
        for (int e = tid; e < NE; e += BLOCK) part += __uint_as_float(sh_key[e]);
        for (int off = 32; off > 0; off >>= 1) part += __shfl_down(part, off, 64);
        if ((tid & 63) == 0) sh_red[tid >> 6] = (double)part;
        __syncthreads();
        if (tid == 0) sh_sn = (float)(sh_red[0] + sh_red[1] + sh_red[2] + sh_red[3]);
        __syncthreads();
    }
    const float sn = sh_sn;

    // ---- per-node gather (reference add order) + conn contribution ----
    double acc = 0.0;
    for (int pix = tid; pix < NNODE; pix += BLOCK) {
        const int r = pix >> 5, c = pix & 31;
        float nw = 0.0f;
        // right edge
        if (c < 31) { const int e = r * 31 + c;
            float v = __uint_as_float(sh_key[e]); if (sn > 0.0f) v = v / sn;
            const float g = sh_t[pix] + sh_t[pix + 1];
            if (sign == 0) { if (g >= 3.0f) v = 0.0f; } else { if (g < 10.0f) v = 0.0f; }
            nw += v; }
        // left edge
        if (c > 0)  { const int e = r * 31 + c - 1;
            float v = __uint_as_float(sh_key[e]); if (sn > 0.0f) v = v / sn;
            const float g = sh_t[pix - 1] + sh_t[pix];
            if (sign == 0) { if (g >= 3.0f) v = 0.0f; } else { if (g < 10.0f) v = 0.0f; }
            nw += v; }
        // down edge
        if (r < 31) { const int e = NH + pix;
            float v = __uint_as_float(sh_key[e]); if (sn > 0.0f) v = v / sn;
            const float g = sh_t[pix] + sh_t[pix + 32];
            if (sign == 0) { if (g >= 3.0f) v = 0.0f; } else { if (g < 10.0f) v = 0.0f; }
            nw += v; }
        // up edge
        if (r > 0)  { const int e = NH + pix - 32;
            float v = __uint_as_float(sh_key[e]); if (sn > 0.0f) v = v / sn;
            const float g = sh_t[pix - 32] + sh_t[pix];
            if (sign == 0) { if (g >= 3.0f) v = 0.0f; } else { if (g < 10.0f) v = 0.0f; }
            nw += v; }
        const float p = sh_p[pix];
        float term;
        if (sign == 0) {
            term = (p * p) * nw;
        } else {
            const float d = 20.0f - p;
            term = (0.1f * (d * d)) * nw;
        }
        acc += (double)term;
    }
    for (int off = 32; off > 0; off >>= 1) acc += __shfl_down(acc, off, 64);
    if ((tid & 63) == 0) sh_red[tid >> 6] = acc;
    __syncthreads();
    if (tid == 0)
        atomicAdd(&acc_ws[1], sh_red[0] + sh_red[1] + sh_red[2] + sh_red[3]);
}

__global__ __launch_bounds__(BLOCK) void mse_kernel(const float* __restrict__ pred,
                                                    const float* __restrict__ tgt,
                                                    double* __restrict__ acc_ws,
                                                    long n) {
    double acc = 0.0;
    for (long i = (long)blockIdx.x * BLOCK + threadIdx.x; i < n; i += (long)gridDim.x * BLOCK) {
        const float d = pred[i] - tgt[i];
        acc += (double)(d * d);
    }
    for (int off = 32; off > 0; off >>= 1) acc += __shfl_down(acc, off, 64);
    __shared__ double red[4];
    if ((threadIdx.x & 63) == 0) red[threadIdx.x >> 6] = acc;
    __syncthreads();
    if (threadIdx.x == 0)
        atomicAdd(&acc_ws[0], red[0] + red[1] + red[2] + red[3]);
}

__global__ void fin_kernel(const double* __restrict__ acc_ws, float* __restrict__ out, long n) {
    if (threadIdx.x == 0 && blockIdx.x == 0) {
        out[0] = (float)(acc_ws[0] / (double)n);
        out[1] = (float)(acc_ws[1] * (double)1e-4f);
    }
}

extern "C" void kernel_launch(void* const* d_in, const int* in_sizes, int n_in,
                              void* d_out, int out_size, void* d_ws, size_t ws_size,
                              hipStream_t stream) {
    const float* pred = (const float*)d_in[0];
    const float* tgt  = (const float*)d_in[1];
    float* out = (float*)d_out;
    double* acc = (double*)d_ws;

    const long n = (long)in_sizes[0];            // 4*1*128*128*128 = 8388608
    const int  B = (int)(n / 2097152);           // batches

    hipMemsetAsync(d_ws, 0, 2 * sizeof(double), stream);
    mse_kernel<<<1024, BLOCK, 0, stream>>>(pred, tgt, acc, n);
    // grid: 24 items x 4 windows x B batches x 2 signs
    conn_kernel<<<192 * B, BLOCK, 0, stream>>>(pred, tgt, acc, B);
    fin_kernel<<<1, 64, 0, stream>>>(acc, out, n);
}

// Round 6
// 767.154 us; speedup vs baseline: 1.1019x; 1.1019x over previous
//
#include <hip/hip_runtime.h>

#define BLOCK 256
#define NNODE 1024
#define NH    992
#define NE    1984
#define NSORT 2048
#define LMAX  12
#define CHUNK 64
#define NPASS (NE / CHUNK)

typedef unsigned long long ull;

__device__ __forceinline__ void edge_nodes(int e, int& a, int& b) {
    if (e < NH) {                 // horizontal: (r,c)-(r,c+1), e = r*31+c
        int r = e / 31;
        int c = e - r * 31;
        a = (r << 5) + c;
        b = a + 1;
    } else {                      // vertical: (r,c)-(r+1,c), e-992 = r*32+c
        a = e - NH;
        b = a + 32;
    }
}

// Parallel-safe find with full path compression. Concurrent lanes may race on
// parent writes, but every written value is an ancestor of the node in the
// (static during this phase) forest, so roots are preserved.
__device__ __forceinline__ int find_par(unsigned short* par, int x) {
    volatile unsigned short* vp = par;
    int r = x;
    int p = vp[r];
    while (p != r) { r = p; p = vp[r]; }
    int c = x;
    while (c != r) { const int nxt = vp[c]; vp[c] = (unsigned short)r; c = nxt; }
    return r;
}

// dot product of 4 packed u16 lanes
__device__ __forceinline__ int dot16x4(ull a, ull b) {
    int s  = (int)(a & 0xFFFFu)         * (int)(b & 0xFFFFu);
    s     += (int)((a >> 16) & 0xFFFFu) * (int)((b >> 16) & 0xFFFFu);
    s     += (int)((a >> 32) & 0xFFFFu) * (int)((b >> 32) & 0xFFFFu);
    s     += (int)((a >> 48) & 0xFFFFu) * (int)((b >> 48) & 0xFFFFu);
    return s;
}

// bitonic compare-exchange on (key, idx), ascending iff up
__device__ __forceinline__ void cswap(unsigned int& ka, unsigned short& ia,
                                      unsigned int& kb, unsigned short& ib, bool up) {
    const bool gt = (ka > kb) || (ka == kb && ia > ib);
    if (gt == up) {
        const unsigned int  tk = ka; ka = kb; kb = tk;
        const unsigned short ti = ia; ia = ib; ib = ti;
    }
}

__global__ __launch_bounds__(BLOCK) void conn_kernel(const float* __restrict__ pred,
                                                     const float* __restrict__ tgt,
                                                     double* __restrict__ acc_ws,
                                                     int B) {
    __shared__ alignas(16) float          sh_p[NNODE];
    __shared__ alignas(16) float          sh_t[NNODE];   // during Kruskal: u32 claim array
    __shared__ alignas(16) unsigned int   sh_key[NSORT];   // sort keys; later reused as w bits
    __shared__ alignas(16) unsigned short sh_idx[NSORT];   // sort payload (edge ids); early: dilate scratch
    __shared__ unsigned short sh_parent[NNODE];       // CC labels, then UF parent
    __shared__ unsigned int   sh_szto[NNODE];         // lo16 = UF size, hi16 = tot; early: root->label map
    __shared__ ull            sh_cnt64[NNODE * 3];    // 12 packed u16 label counts per node
    __shared__ unsigned char  sh_seg[NNODE];          // early: mask / fg
    __shared__ int            sh_flag;
    __shared__ int            sh_L;
    __shared__ float          sh_sn;
    __shared__ double         sh_red[4];

    const int tid = threadIdx.x;
    int wg = blockIdx.x;
    // XCD pair-swizzle: dispatch round-robins XCD = blockIdx % 8. Take sign
    // from bit 3 so the two sign-blocks (identical projection reads) land on
    // the SAME XCD and share L2. Grid = 192*B is divisible by 16.
    const int sign = (wg >> 3) & 1;                   // 0 = neg, 1 = pos
    wg = (wg & 7) | ((wg >> 4) << 3);                 // compact remaining bits
    const int b    = wg % B;  wg /= B;
    const int win  = wg & 3;  wg >>= 2;
    const int item = wg;                              // 0..23
    const int axis_id = item % 3;                     // 0:reduce z(H), 1:reduce y(W), 2:reduce x(D)
    const int cube = item / 3;
    const int ci = cube & 1;                          // x block
    const int cj = (cube >> 1) & 1;                   // y block
    const int ck = (cube >> 2) & 1;                   // z block
    const int wk = win >> 1;                          // window row block
    const int wj = win & 1;                           // window col block

    const size_t base = (size_t)b * 2097152u;

    // ---- projection mins (32x32 window of the 64x64 projection) ----
    if (axis_id == 2) {
        // reduced axis contiguous: float4 along the reduction
        for (int pix = tid; pix < NNODE; pix += BLOCK) {
            const int r = pix >> 5, c = pix & 31;
            const int R = wk * 32 + r, C = wj * 32 + c;
            const size_t idx0 = base + (size_t)(ck * 64 + R) * 16384u + (size_t)(cj * 64 + C) * 128u + (size_t)(ci * 64);
            const float4* pp = reinterpret_cast<const float4*>(pred + idx0);
            const float4* tp = reinterpret_cast<const float4*>(tgt + idx0);
            float pm = 3.4e38f, tm = 3.4e38f;
            #pragma unroll
            for (int h = 0; h < 16; ++h) {
                const float4 a = pp[h];
                const float4 t = tp[h];
                pm = fminf(pm, fminf(fminf(a.x, a.y), fminf(a.z, a.w)));
                tm = fminf(tm, fminf(fminf(t.x, t.y), fminf(t.z, t.w)));
            }
            sh_p[pix] = pm;
            sh_t[pix] = tm;
        }
    } else {
        // reduced axis strided: float4 along the window's contiguous x axis.
        // thread t owns row r = t>>3, cols c0..c0+3 with c0 = (t&7)*4.
        const int r  = tid >> 3;
        const int c0 = (tid & 7) << 2;
        const int R = wk * 32 + r, C = wj * 32 + c0;
        size_t idx0; int hstride;
        if (axis_id == 0) {
            idx0 = base + (size_t)(ck * 64) * 16384u + (size_t)(cj * 64 + R) * 128u + (size_t)(ci * 64 + C);
            hstride = 16384;
        } else {
            idx0 = base + (size_t)(ck * 64 + R) * 16384u + (size_t)(cj * 64) * 128u + (size_t)(ci * 64 + C);
            hstride = 128;
        }
        float4 pm = make_float4(3.4e38f, 3.4e38f, 3.4e38f, 3.4e38f);
        float4 tm = pm;
        #pragma unroll 8
        for (int h = 0; h < 64; ++h) {
            const float4 a  = *reinterpret_cast<const float4*>(pred + idx0);
            const float4 t4 = *reinterpret_cast<const float4*>(tgt + idx0);
            pm.x = fminf(pm.x, a.x);  pm.y = fminf(pm.y, a.y);
            pm.z = fminf(pm.z, a.z);  pm.w = fminf(pm.w, a.w);
            tm.x = fminf(tm.x, t4.x); tm.y = fminf(tm.y, t4.y);
            tm.z = fminf(tm.z, t4.z); tm.w = fminf(tm.w, t4.w);
            idx0 += (size_t)hstride;
        }
        *reinterpret_cast<float4*>(&sh_p[(r << 5) + c0]) = pm;
        *reinterpret_cast<float4*>(&sh_t[(r << 5) + c0]) = tm;
    }
    __syncthreads();

    // ---- dilate5 of (t == 0), von Neumann, zero padded, window-local ----
    unsigned char* mA = sh_seg;
    unsigned char* mB = (unsigned char*)sh_idx;
    for (int pix = tid; pix < NNODE; pix += BLOCK)
        mA[pix] = (sh_t[pix] == 0.0f) ? 1 : 0;
    __syncthreads();
    for (int it = 0; it < 5; ++it) {
        unsigned char* src = (it & 1) ? mB : mA;
        unsigned char* dst = (it & 1) ? mA : mB;
        for (int pix = tid; pix < NNODE; pix += BLOCK) {
            const int r = pix >> 5, c = pix & 31;
            unsigned char v = src[pix];
            if (r > 0)  v |= src[pix - 32];
            if (r < 31) v |= src[pix + 32];
            if (c > 0)  v |= src[pix - 1];
            if (c < 31) v |= src[pix + 1];
            dst[pix] = v;
        }
        __syncthreads();
    }
    // result in mB; fg = !mB into mA
    for (int pix = tid; pix < NNODE; pix += BLOCK)
        mA[pix] = mB[pix] ^ 1;
    __syncthreads();

    // ---- 8-connected CC labeling on fg via min-index propagation ----
    for (int pix = tid; pix < NNODE; pix += BLOCK)
        sh_parent[pix] = mA[pix] ? (unsigned short)pix : (unsigned short)0xFFFF;
    __syncthreads();
    for (;;) {
        if (tid == 0) sh_flag = 0;
        __syncthreads();
        for (int pix = tid; pix < NNODE; pix += BLOCK) {
            if (!mA[pix]) continue;
            const int r = pix >> 5, c = pix & 31;
            int m = sh_parent[pix];
            #pragma unroll
            for (int d = 0; d < 8; ++d) {
                static const int dr[8] = {-1,-1,-1, 0, 0, 1, 1, 1};
                static const int dc[8] = {-1, 0, 1,-1, 1,-1, 0, 1};
                const int rr = r + dr[d], cc = c + dc[d];
                if (rr < 0 || rr > 31 || cc < 0 || cc > 31) continue;
                const int nb = (rr << 5) + cc;
                if (mA[nb]) { int v = sh_parent[nb]; if (v < m) m = v; }
            }
            while ((int)sh_parent[m] < m) m = sh_parent[m];
            if (m < (int)sh_parent[pix]) { sh_parent[pix] = (unsigned short)m; sh_flag = 1; }
        }
        __syncthreads();
        const int f = sh_flag;
        __syncthreads();
        if (f == 0) break;
    }

    // ---- compact labels (equality is all that matters) ----
    if (tid == 0) sh_L = 0;
    __syncthreads();
    for (int pix = tid; pix < NNODE; pix += BLOCK) {
        if (mA[pix] && (int)sh_parent[pix] == pix) {
            const int id = atomicAdd(&sh_L, 1);
            sh_szto[pix] = (unsigned int)(id + 1);    // root -> label map
        }
    }
    __syncthreads();
    for (int pix = tid; pix < NNODE; pix += BLOCK) {
        unsigned char s = 0;
        if (mA[pix]) {
            int lab = (int)sh_szto[sh_parent[pix]];
            if (lab > 255) lab = 255;
            s = (unsigned char)lab;
        }
        sh_seg[pix] = s;   // overwrites mA (fg) — per-pixel read precedes write
    }
    __syncthreads();

    // ---- union-find init (packed: szto = size | tot<<16; cnt = 3x u64 of 4x u16) ----
    for (int pix = tid; pix < NNODE; pix += BLOCK) {
        sh_parent[pix] = (unsigned short)pix;
        const int s = sh_seg[pix];
        const unsigned int tot = (s > 0 && s <= LMAX) ? 1u : 0u;
        sh_szto[pix] = 1u | (tot << 16);
        ull c0 = 0, c1 = 0, c2 = 0;
        if (s >= 1 && s <= LMAX) {
            const ull bit = 1ull << (((s - 1) & 3) * 16);
            const int q = (s - 1) >> 2;
            if (q == 0) c0 = bit; else if (q == 1) c1 = bit; else c2 = bit;
        }
        sh_cnt64[pix * 3 + 0] = c0;
        sh_cnt64[pix * 3 + 1] = c1;
        sh_cnt64[pix * 3 + 2] = c2;
    }
    __syncthreads();   // sh_p/sh_t stable; register build below reads them

    // ---- build sort keys DIRECTLY in registers (thread t owns elements 8t..8t+7)
    //      and run the k=2,4,8 bitonic rounds in-register before first store ----
    unsigned int   K[8];
    unsigned short I[8];
    const int b8 = tid << 3;
    #pragma unroll
    for (int l = 0; l < 8; ++l) {
        const int e = b8 + l;
        if (e < NE) {
            int a, bb; edge_nodes(e, a, bb);
            float cost = sh_p[a] + sh_p[bb];
            const float g = sh_t[a] + sh_t[bb];
            if (sign == 0) { if (g > 10.0f) cost = 10.0f; }
            else           { if (g <  3.0f) cost = 0.0f;  }
            K[l] = ~__float_as_uint(cost);
            I[l] = (unsigned short)e;
        } else {
            K[l] = 0xFFFFFFFFu;
            I[l] = (unsigned short)0xFFFF;
        }
    }
    // k=2, j=1 (up by (i&2)==0)
    cswap(K[0],I[0],K[1],I[1], true );
    cswap(K[2],I[2],K[3],I[3], false);
    cswap(K[4],I[4],K[5],I[5], true );
    cswap(K[6],I[6],K[7],I[7], false);
    // k=4, j=2 (up by (i&4)==0)
    cswap(K[0],I[0],K[2],I[2], true );
    cswap(K[1],I[1],K[3],I[3], true );
    cswap(K[4],I[4],K[6],I[6], false);
    cswap(K[5],I[5],K[7],I[7], false);
    // k=4, j=1
    cswap(K[0],I[0],K[1],I[1], true );
    cswap(K[2],I[2],K[3],I[3], true );
    cswap(K[4],I[4],K[5],I[5], false);
    cswap(K[6],I[6],K[7],I[7], false);
    // k=8: up uniform per thread = ((b8 & 8) == 0)
    {
        const bool u8 = ((b8 & 8) == 0);
        cswap(K[0],I[0],K[4],I[4], u8); cswap(K[1],I[1],K[5],I[5], u8);
        cswap(K[2],I[2],K[6],I[6], u8); cswap(K[3],I[3],K[7],I[7], u8);
        cswap(K[0],I[0],K[2],I[2], u8); cswap(K[1],I[1],K[3],I[3], u8);
        cswap(K[4],I[4],K[6],I[6], u8); cswap(K[5],I[5],K[7],I[7], u8);
        cswap(K[0],I[0],K[1],I[1], u8); cswap(K[2],I[2],K[3],I[3], u8);
        cswap(K[4],I[4],K[5],I[5], u8); cswap(K[6],I[6],K[7],I[7], u8);
    }
    // store session
    {
        uint4 k0, k1, iv;
        k0.x=K[0]; k0.y=K[1]; k0.z=K[2]; k0.w=K[3];
        k1.x=K[4]; k1.y=K[5]; k1.z=K[6]; k1.w=K[7];
        iv.x=(unsigned int)I[0] | ((unsigned int)I[1]<<16);
        iv.y=(unsigned int)I[2] | ((unsigned int)I[3]<<16);
        iv.z=(unsigned int)I[4] | ((unsigned int)I[5]<<16);
        iv.w=(unsigned int)I[6] | ((unsigned int)I[7]<<16);
        *reinterpret_cast<uint4*>(&sh_key[b8])     = k0;
        *reinterpret_cast<uint4*>(&sh_key[b8 + 4]) = k1;
        *reinterpret_cast<uint4*>(&sh_idx[b8])     = iv;
    }
    __syncthreads();

    // ---- bitonic rounds k=16..2048: j>=8 via LDS (pair-indexed, all threads
    //      active), j=4,2,1 tail in registers ----
    for (int k = 16; k <= NSORT; k <<= 1) {
        for (int j = k >> 1; j >= 8; j >>= 1) {
            for (int p = tid; p < (NSORT >> 1); p += BLOCK) {
                const int i   = ((p & ~(j - 1)) << 1) | (p & (j - 1));
                const int ixj = i | j;
                const unsigned int ka = sh_key[i], kb = sh_key[ixj];
                const unsigned short ia = sh_idx[i], ib = sh_idx[ixj];
                const bool gt = (ka > kb) || (ka == kb && ia > ib);
                const bool up = ((i & k) == 0);
                if (gt == up) {
                    sh_key[i] = kb; sh_key[ixj] = ka;
                    sh_idx[i] = ib; sh_idx[ixj] = ia;
                }
            }
            __syncthreads();
        }
        // register tail: j = 4, 2, 1 (direction uniform within the 8-block)
        {
            const uint4 k0 = *reinterpret_cast<const uint4*>(&sh_key[b8]);
            const uint4 k1 = *reinterpret_cast<const uint4*>(&sh_key[b8 + 4]);
            const uint4 iv = *reinterpret_cast<const uint4*>(&sh_idx[b8]);
            K[0]=k0.x; K[1]=k0.y; K[2]=k0.z; K[3]=k0.w;
            K[4]=k1.x; K[5]=k1.y; K[6]=k1.z; K[7]=k1.w;
            I[0]=(unsigned short)(iv.x); I[1]=(unsigned short)(iv.x>>16);
            I[2]=(unsigned short)(iv.y); I[3]=(unsigned short)(iv.y>>16);
            I[4]=(unsigned short)(iv.z); I[5]=(unsigned short)(iv.z>>16);
            I[6]=(unsigned short)(iv.w); I[7]=(unsigned short)(iv.w>>16);
            const bool u8 = ((b8 & k) == 0);
            cswap(K[0],I[0],K[4],I[4], u8); cswap(K[1],I[1],K[5],I[5], u8);
            cswap(K[2],I[2],K[6],I[6], u8); cswap(K[3],I[3],K[7],I[7], u8);
            cswap(K[0],I[0],K[2],I[2], u8); cswap(K[1],I[1],K[3],I[3], u8);
            cswap(K[4],I[4],K[6],I[6], u8); cswap(K[5],I[5],K[7],I[7], u8);
            cswap(K[0],I[0],K[1],I[1], u8); cswap(K[2],I[2],K[3],I[3], u8);
            cswap(K[4],I[4],K[5],I[5], u8); cswap(K[6],I[6],K[7],I[7], u8);
            uint4 o0, o1, ov;
            o0.x=K[0]; o0.y=K[1]; o0.z=K[2]; o0.w=K[3];
            o1.x=K[4]; o1.y=K[5]; o1.z=K[6]; o1.w=K[7];
            ov.x=(unsigned int)I[0] | ((unsigned int)I[1]<<16);
            ov.y=(unsigned int)I[2] | ((unsigned int)I[3]<<16);
            ov.z=(unsigned int)I[4] | ((unsigned int)I[5]<<16);
            ov.w=(unsigned int)I[6] | ((unsigned int)I[7]<<16);
            *reinterpret_cast<uint4*>(&sh_key[b8])     = o0;
            *reinterpret_cast<uint4*>(&sh_key[b8 + 4]) = o1;
            *reinterpret_cast<uint4*>(&sh_idx[b8])     = ov;
        }
        __syncthreads();
    }

    // ---- zero edge weights (reuse key array as float bits) ----
    for (int e = tid; e < NE; e += BLOCK) sh_key[e] = 0u;   // 0.0f
    __syncthreads();

    // ---- save sh_t into registers; its 4 KB becomes the claim array ----
    float t_save[4];
    #pragma unroll
    for (int q = 0; q < 4; ++q) t_save[q] = sh_t[tid + q * BLOCK];
    __syncthreads();
    unsigned int* claim = reinterpret_cast<unsigned int*>(sh_t);
    #pragma unroll
    for (int q = 0; q < 4; ++q) claim[tid + q * BLOCK] = 0xFFFFFFFFu;
    __syncthreads();

    // ---- single-wave Kruskal with claim-based parallel commit (wave 0) ----
    // Exactness: lane l may commit in a round iff NO pending lane j<l shares a
    // root with l. "j<l shares a root" == "j<l claims claim[ra_l] or
    // claim[rb_l]" — so l wins iff it is the min claimant of BOTH its roots
    // (one atomicMin each + two reads). The committed set is the greedy
    // prefix-independent set: every committed lane sees exactly the
    // serial-prefix component state (lanes <l that touch l's components are
    // all pending -> block l; lanes >l never touch them). Winners commit in
    // parallel to provably disjoint roots. Min pending lane always wins ->
    // guaranteed progress. All coordination is O(1) wave-ops per round.
    if (tid < 64) {
        const int lane = tid;
        for (int pass = 0; pass < NPASS; ++pass) {
            const int e = sh_idx[pass * CHUNK + lane];
            int a, bb; edge_nodes(e, a, bb);
            int ra = find_par(sh_parent, a);
            int rb = find_par(sh_parent, bb);
            bool pend = (ra != rb);
            ull P = __ballot(pend);
            while (P) {
                if (pend) {
                    atomicMin(&claim[ra], (unsigned int)lane);
                    atomicMin(&claim[rb], (unsigned int)lane);
                }
                asm volatile("s_waitcnt lgkmcnt(0)" ::: "memory");
                __builtin_amdgcn_sched_barrier(0);
                bool win = false;
                if (pend)
                    win = (claim[ra] == (unsigned int)lane) && (claim[rb] == (unsigned int)lane);
                if (win) {
                    // parallel commit: roots disjoint across winners
                    const unsigned int xa = sh_szto[ra], xb = sh_szto[rb];
                    const ull a0 = sh_cnt64[ra * 3 + 0];
                    const ull a1 = sh_cnt64[ra * 3 + 1];
                    const ull a2 = sh_cnt64[ra * 3 + 2];
                    const ull b0 = sh_cnt64[rb * 3 + 0];
                    const ull b1 = sh_cnt64[rb * 3 + 1];
                    const ull b2 = sh_cnt64[rb * 3 + 2];
                    const int ta = (int)(xa >> 16), tb = (int)(xb >> 16);
                    const int same = dot16x4(a0, b0) + dot16x4(a1, b1) + dot16x4(a2, b2);
                    const int wv = sign ? same : (ta * tb - same);
                    // survivor = larger component (weight symmetric; union by size)
                    const int big = ((xa & 0xFFFFu) > (xb & 0xFFFFu));
                    const int rs = big ? ra : rb;
                    const int rl = big ? rb : ra;
                    sh_key[e] = __float_as_uint((float)wv);
                    // per-lane sums <= 1024 -> no cross-lane carry
                    sh_cnt64[rs * 3 + 0] = a0 + b0;
                    sh_cnt64[rs * 3 + 1] = a1 + b1;
                    sh_cnt64[rs * 3 + 2] = a2 + b2;
                    // size sum <= 2048, tot sum <= 2048 -> no field carry
                    sh_szto[rs] = xa + xb;
                    sh_parent[rl] = (unsigned short)rs;
                }
                // reset claims (benign same-value races among co-claimants);
                // DS ops are processed in program order per wave, so these
                // land after the reads above and before next round's atomicMin
                if (pend) {
                    claim[ra] = 0xFFFFFFFFu;
                    claim[rb] = 0xFFFFFFFFu;
                }
                asm volatile("s_waitcnt lgkmcnt(0)" ::: "memory");
                __builtin_amdgcn_sched_barrier(0);
                if (win) pend = false;
                if (pend) {
                    ra = find_par(sh_parent, ra);
                    rb = find_par(sh_parent, rb);
                    pend = (ra != rb);
                }
                P = __ballot(pend);
            }
        }
    }
    __syncthreads();

    // ---- restore sh_t ----
    #pragma unroll
    for (int q = 0; q < 4; ++q) sh_t[tid + q * BLOCK] = t_save[q];
    __syncthreads();

    // ---- normalization sum (all weights integer-valued < 2^24: exact) ----
    {
        float part = 0.0f;
        for (int e = tid; e < NE; e += BLOCK) part += __uint_as_float(sh_key[e]);
        for (int off = 32; off > 0; off >>= 1) part += __shfl_down(part, off, 64);
        if ((tid & 63) == 0) sh_red[tid >> 6] = (double)part;
        __syncthreads();
        if (tid == 0) sh_sn = (float)(sh_red[0] + sh_red[1] + sh_red[2] + sh_red[3]);
        __syncthreads();
    }
    const float sn = sh_sn;

    // ---- per-node gather (reference add order) + conn contribution ----
    double acc = 0.0;
    for (int pix = tid; pix < NNODE; pix += BLOCK) {
        const int r = pix >> 5, c = pix & 31;
        float nw = 0.0f;
        // right edge
        if (c < 31) { const int e = r * 31 + c;
            float v = __uint_as_float(sh_key[e]); if (sn > 0.0f) v = v / sn;
            const float g = sh_t[pix] + sh_t[pix + 1];
            if (sign == 0) { if (g >= 3.0f) v = 0.0f; } else { if (g < 10.0f) v = 0.0f; }
            nw += v; }
        // left edge
        if (c > 0)  { const int e = r * 31 + c - 1;
            float v = __uint_as_float(sh_key[e]); if (sn > 0.0f) v = v / sn;
            const float g = sh_t[pix - 1] + sh_t[pix];
            if (sign == 0) { if (g >= 3.0f) v = 0.0f; } else { if (g < 10.0f) v = 0.0f; }
            nw += v; }
        // down edge
        if (r < 31) { const int e = NH + pix;
            float v = __uint_as_float(sh_key[e]); if (sn > 0.0f) v = v / sn;
            const float g = sh_t[pix] + sh_t[pix + 32];
            if (sign == 0) { if (g >= 3.0f) v = 0.0f; } else { if (g < 10.0f) v = 0.0f; }
            nw += v; }
        // up edge
        if (r > 0)  { const int e = NH + pix - 32;
            float v = __uint_as_float(sh_key[e]); if (sn > 0.0f) v = v / sn;
            const float g = sh_t[pix - 32] + sh_t[pix];
            if (sign == 0) { if (g >= 3.0f) v = 0.0f; } else { if (g < 10.0f) v = 0.0f; }
            nw += v; }
        const float p = sh_p[pix];
        float term;
        if (sign == 0) {
            term = (p * p) * nw;
        } else {
            const float d = 20.0f - p;
            term = (0.1f * (d * d)) * nw;
        }
        acc += (double)term;
    }
    for (int off = 32; off > 0; off >>= 1) acc += __shfl_down(acc, off, 64);
    if ((tid & 63) == 0) sh_red[tid >> 6] = acc;
    __syncthreads();
    if (tid == 0)
        atomicAdd(&acc_ws[1], sh_red[0] + sh_red[1] + sh_red[2] + sh_red[3]);
}

__global__ __launch_bounds__(BLOCK) void mse_kernel(const float* __restrict__ pred,
                                                    const float* __restrict__ tgt,
                                                    double* __restrict__ acc_ws,
                                                    long n) {
    double acc = 0.0;
    for (long i = (long)blockIdx.x * BLOCK + threadIdx.x; i < n; i += (long)gridDim.x * BLOCK) {
        const float d = pred[i] - tgt[i];
        acc += (double)(d * d);
    }
    for (int off = 32; off > 0; off >>= 1) acc += __shfl_down(acc, off, 64);
    __shared__ double red[4];
    if ((threadIdx.x & 63) == 0) red[threadIdx.x >> 6] = acc;
    __syncthreads();
    if (threadIdx.x == 0)
        atomicAdd(&acc_ws[0], red[0] + red[1] + red[2] + red[3]);
}

__global__ void fin_kernel(const double* __restrict__ acc_ws, float* __restrict__ out, long n) {
    if (threadIdx.x == 0 && blockIdx.x == 0) {
        out[0] = (float)(acc_ws[0] / (double)n);
        out[1] = (float)(acc_ws[1] * (double)1e-4f);
    }
}

extern "C" void kernel_launch(void* const* d_in, const int* in_sizes, int n_in,
                              void* d_out, int out_size, void* d_ws, size_t ws_size,
                              hipStream_t stream) {
    const float* pred = (const float*)d_in[0];
    const float* tgt  = (const float*)d_in[1];
    float* out = (float*)d_out;
    double* acc = (double*)d_ws;

    const long n = (long)in_sizes[0];            // 4*1*128*128*128 = 8388608
    const int  B = (int)(n / 2097152);           // batches

    hipMemsetAsync(d_ws, 0, 2 * sizeof(double), stream);
    mse_kernel<<<1024, BLOCK, 0, stream>>>(pred, tgt, acc, n);
    // grid: 24 items x 4 windows x B batches x 2 signs
    conn_kernel<<<192 * B, BLOCK, 0, stream>>>(pred, tgt, acc, B);
    fin_kernel<<<1, 64, 0, stream>>>(acc, out, n);
}

// Round 7
// 530.716 us; speedup vs baseline: 1.5928x; 1.4455x over previous
//
#include <hip/hip_runtime.h>

#define BLOCK 256
#define NNODE 1024
#define NH    992
#define NE    1984
#define NSORT 2048
#define LMAX  12
#define CHUNK 64
#define NPASS (NE / CHUNK)

typedef unsigned long long ull;

__device__ __forceinline__ void edge_nodes(int e, int& a, int& b) {
    if (e < NH) {                 // horizontal: (r,c)-(r,c+1), e = r*31+c
        int r = e / 31;
        int c = e - r * 31;
        a = (r << 5) + c;
        b = a + 1;
    } else {                      // vertical: (r,c)-(r+1,c), e-992 = r*32+c
        a = e - NH;
        b = a + 32;
    }
}

// Parallel-safe find with full path compression. Concurrent lanes may race on
// parent writes, but every written value is an ancestor of the node in the
// (static during this phase) forest, so roots are preserved.
__device__ __forceinline__ int find_par(unsigned short* par, int x) {
    volatile unsigned short* vp = par;
    int r = x;
    int p = vp[r];
    while (p != r) { r = p; p = vp[r]; }
    int c = x;
    while (c != r) { const int nxt = vp[c]; vp[c] = (unsigned short)r; c = nxt; }
    return r;
}

// dot product of 4 packed u16 lanes
__device__ __forceinline__ int dot16x4(ull a, ull b) {
    int s  = (int)(a & 0xFFFFu)         * (int)(b & 0xFFFFu);
    s     += (int)((a >> 16) & 0xFFFFu) * (int)((b >> 16) & 0xFFFFu);
    s     += (int)((a >> 32) & 0xFFFFu) * (int)((b >> 32) & 0xFFFFu);
    s     += (int)((a >> 48) & 0xFFFFu) * (int)((b >> 48) & 0xFFFFu);
    return s;
}

// bitonic compare-exchange on (key, idx), ascending iff up
__device__ __forceinline__ void cswap(unsigned int& ka, unsigned short& ia,
                                      unsigned int& kb, unsigned short& ib, bool up) {
    const bool gt = (ka > kb) || (ka == kb && ia > ib);
    if (gt == up) {
        const unsigned int  tk = ka; ka = kb; kb = tk;
        const unsigned short ti = ia; ia = ib; ib = ti;
    }
}

__global__ __launch_bounds__(BLOCK) void conn_kernel(const float* __restrict__ pred,
                                                     const float* __restrict__ tgt,
                                                     double* __restrict__ acc_ws,
                                                     int B) {
    __shared__ alignas(16) float          sh_p[NNODE];
    __shared__ alignas(16) float          sh_t[NNODE];
    __shared__ alignas(16) unsigned int   sh_key[NSORT];   // sort keys; later reused as w bits
    __shared__ alignas(16) unsigned short sh_idx[NSORT];   // sort payload (edge ids); early: dilate scratch
    __shared__ unsigned short sh_parent[NNODE];       // CC labels, then UF parent
    __shared__ unsigned int   sh_szto[NNODE];         // lo16 = UF size, hi16 = tot; early: root->label map
    __shared__ ull            sh_cnt64[NNODE * 3];    // 12 packed u16 label counts per node
    __shared__ unsigned char  sh_seg[NNODE];          // early: mask / fg
    __shared__ int            sh_flag;
    __shared__ int            sh_L;
    __shared__ float          sh_sn;
    __shared__ double         sh_red[4];

    const int tid = threadIdx.x;
    int wg = blockIdx.x;
    // XCD pair-swizzle: dispatch round-robins XCD = blockIdx % 8. Take sign
    // from bit 3 so the two sign-blocks (identical projection reads) land on
    // the SAME XCD and share L2. Grid = 192*B is divisible by 16.
    const int sign = (wg >> 3) & 1;                   // 0 = neg, 1 = pos
    wg = (wg & 7) | ((wg >> 4) << 3);                 // compact remaining bits
    const int b    = wg % B;  wg /= B;
    const int win  = wg & 3;  wg >>= 2;
    const int item = wg;                              // 0..23
    const int axis_id = item % 3;                     // 0:reduce z(H), 1:reduce y(W), 2:reduce x(D)
    const int cube = item / 3;
    const int ci = cube & 1;                          // x block
    const int cj = (cube >> 1) & 1;                   // y block
    const int ck = (cube >> 2) & 1;                   // z block
    const int wk = win >> 1;                          // window row block
    const int wj = win & 1;                           // window col block

    const size_t base = (size_t)b * 2097152u;

    // ---- projection mins (32x32 window of the 64x64 projection) ----
    if (axis_id == 2) {
        // reduced axis contiguous: float4 along the reduction
        for (int pix = tid; pix < NNODE; pix += BLOCK) {
            const int r = pix >> 5, c = pix & 31;
            const int R = wk * 32 + r, C = wj * 32 + c;
            const size_t idx0 = base + (size_t)(ck * 64 + R) * 16384u + (size_t)(cj * 64 + C) * 128u + (size_t)(ci * 64);
            const float4* pp = reinterpret_cast<const float4*>(pred + idx0);
            const float4* tp = reinterpret_cast<const float4*>(tgt + idx0);
            float pm = 3.4e38f, tm = 3.4e38f;
            #pragma unroll
            for (int h = 0; h < 16; ++h) {
                const float4 a = pp[h];
                const float4 t = tp[h];
                pm = fminf(pm, fminf(fminf(a.x, a.y), fminf(a.z, a.w)));
                tm = fminf(tm, fminf(fminf(t.x, t.y), fminf(t.z, t.w)));
            }
            sh_p[pix] = pm;
            sh_t[pix] = tm;
        }
    } else {
        // reduced axis strided: float4 along the window's contiguous x axis.
        // thread t owns row r = t>>3, cols c0..c0+3 with c0 = (t&7)*4.
        const int r  = tid >> 3;
        const int c0 = (tid & 7) << 2;
        const int R = wk * 32 + r, C = wj * 32 + c0;
        size_t idx0; int hstride;
        if (axis_id == 0) {
            idx0 = base + (size_t)(ck * 64) * 16384u + (size_t)(cj * 64 + R) * 128u + (size_t)(ci * 64 + C);
            hstride = 16384;
        } else {
            idx0 = base + (size_t)(ck * 64 + R) * 16384u + (size_t)(cj * 64) * 128u + (size_t)(ci * 64 + C);
            hstride = 128;
        }
        float4 pm = make_float4(3.4e38f, 3.4e38f, 3.4e38f, 3.4e38f);
        float4 tm = pm;
        #pragma unroll 8
        for (int h = 0; h < 64; ++h) {
            const float4 a  = *reinterpret_cast<const float4*>(pred + idx0);
            const float4 t4 = *reinterpret_cast<const float4*>(tgt + idx0);
            pm.x = fminf(pm.x, a.x);  pm.y = fminf(pm.y, a.y);
            pm.z = fminf(pm.z, a.z);  pm.w = fminf(pm.w, a.w);
            tm.x = fminf(tm.x, t4.x); tm.y = fminf(tm.y, t4.y);
            tm.z = fminf(tm.z, t4.z); tm.w = fminf(tm.w, t4.w);
            idx0 += (size_t)hstride;
        }
        *reinterpret_cast<float4*>(&sh_p[(r << 5) + c0]) = pm;
        *reinterpret_cast<float4*>(&sh_t[(r << 5) + c0]) = tm;
    }
    __syncthreads();

    // ---- dilate5 of (t == 0), von Neumann, zero padded, window-local ----
    unsigned char* mA = sh_seg;
    unsigned char* mB = (unsigned char*)sh_idx;
    for (int pix = tid; pix < NNODE; pix += BLOCK)
        mA[pix] = (sh_t[pix] == 0.0f) ? 1 : 0;
    __syncthreads();
    for (int it = 0; it < 5; ++it) {
        unsigned char* src = (it & 1) ? mB : mA;
        unsigned char* dst = (it & 1) ? mA : mB;
        for (int pix = tid; pix < NNODE; pix += BLOCK) {
            const int r = pix >> 5, c = pix & 31;
            unsigned char v = src[pix];
            if (r > 0)  v |= src[pix - 32];
            if (r < 31) v |= src[pix + 32];
            if (c > 0)  v |= src[pix - 1];
            if (c < 31) v |= src[pix + 1];
            dst[pix] = v;
        }
        __syncthreads();
    }
    // result in mB; fg = !mB into mA
    for (int pix = tid; pix < NNODE; pix += BLOCK)
        mA[pix] = mB[pix] ^ 1;
    __syncthreads();

    // ---- 8-connected CC labeling on fg via min-index propagation ----
    for (int pix = tid; pix < NNODE; pix += BLOCK)
        sh_parent[pix] = mA[pix] ? (unsigned short)pix : (unsigned short)0xFFFF;
    __syncthreads();
    for (;;) {
        if (tid == 0) sh_flag = 0;
        __syncthreads();
        for (int pix = tid; pix < NNODE; pix += BLOCK) {
            if (!mA[pix]) continue;
            const int r = pix >> 5, c = pix & 31;
            int m = sh_parent[pix];
            #pragma unroll
            for (int d = 0; d < 8; ++d) {
                static const int dr[8] = {-1,-1,-1, 0, 0, 1, 1, 1};
                static const int dc[8] = {-1, 0, 1,-1, 1,-1, 0, 1};
                const int rr = r + dr[d], cc = c + dc[d];
                if (rr < 0 || rr > 31 || cc < 0 || cc > 31) continue;
                const int nb = (rr << 5) + cc;
                if (mA[nb]) { int v = sh_parent[nb]; if (v < m) m = v; }
            }
            while ((int)sh_parent[m] < m) m = sh_parent[m];
            if (m < (int)sh_parent[pix]) { sh_parent[pix] = (unsigned short)m; sh_flag = 1; }
        }
        __syncthreads();
        const int f = sh_flag;
        __syncthreads();
        if (f == 0) break;
    }

    // ---- compact labels (equality is all that matters) ----
    if (tid == 0) sh_L = 0;
    __syncthreads();
    for (int pix = tid; pix < NNODE; pix += BLOCK) {
        if (mA[pix] && (int)sh_parent[pix] == pix) {
            const int id = atomicAdd(&sh_L, 1);
            sh_szto[pix] = (unsigned int)(id + 1);    // root -> label map
        }
    }
    __syncthreads();
    for (int pix = tid; pix < NNODE; pix += BLOCK) {
        unsigned char s = 0;
        if (mA[pix]) {
            int lab = (int)sh_szto[sh_parent[pix]];
            if (lab > 255) lab = 255;
            s = (unsigned char)lab;
        }
        sh_seg[pix] = s;   // overwrites mA (fg) — per-pixel read precedes write
    }
    __syncthreads();

    // ---- L-mode specialization (block-uniform) ----
    // L==1: every component's cnt vector is (tot) on label 1 -> same == ta*tb
    //   exactly. Hence neg weights (ta*tb - same) are ALL zero, and pos
    //   weights are ta*tb with no histograms needed.
    // L==0: all weights zero.
    // Zero-weight blocks contribute exactly 0.0 to the conn sum (reference
    //   leaves en as zeros: sn=0 -> no normalize -> nwt=0) -> skip everything.
    const int Lraw = sh_L;
    const int mode = (Lraw <= 1) ? 0 : ((Lraw <= 4) ? 1 : 2);  // 0: no hist, 1: 1-word, 2: 3-word
    const bool skip_all = (Lraw == 0) || (Lraw == 1 && sign == 0);

    if (!skip_all) {

    // ---- union-find init (packed: szto = size | tot<<16; cnt words by mode) ----
    for (int pix = tid; pix < NNODE; pix += BLOCK) {
        sh_parent[pix] = (unsigned short)pix;
        const int s = sh_seg[pix];
        const unsigned int tot = (s > 0 && s <= LMAX) ? 1u : 0u;
        sh_szto[pix] = 1u | (tot << 16);
        if (mode >= 1) {
            ull c0 = 0, c1 = 0, c2 = 0;
            if (s >= 1 && s <= LMAX) {
                const ull bit = 1ull << (((s - 1) & 3) * 16);
                const int q = (s - 1) >> 2;
                if (q == 0) c0 = bit; else if (q == 1) c1 = bit; else c2 = bit;
            }
            sh_cnt64[pix * 3 + 0] = c0;
            if (mode == 2) {
                sh_cnt64[pix * 3 + 1] = c1;
                sh_cnt64[pix * 3 + 2] = c2;
            }
        }
    }
    __syncthreads();

    // ---- build sort keys DIRECTLY in registers (thread t owns elements 8t..8t+7)
    //      and run the k=2,4,8 bitonic rounds in-register before first store ----
    unsigned int   K[8];
    unsigned short I[8];
    const int b8 = tid << 3;
    #pragma unroll
    for (int l = 0; l < 8; ++l) {
        const int e = b8 + l;
        if (e < NE) {
            int a, bb; edge_nodes(e, a, bb);
            float cost = sh_p[a] + sh_p[bb];
            const float g = sh_t[a] + sh_t[bb];
            if (sign == 0) { if (g > 10.0f) cost = 10.0f; }
            else           { if (g <  3.0f) cost = 0.0f;  }
            K[l] = ~__float_as_uint(cost);
            I[l] = (unsigned short)e;
        } else {
            K[l] = 0xFFFFFFFFu;
            I[l] = (unsigned short)0xFFFF;
        }
    }
    // k=2, j=1 (up by (i&2)==0)
    cswap(K[0],I[0],K[1],I[1], true );
    cswap(K[2],I[2],K[3],I[3], false);
    cswap(K[4],I[4],K[5],I[5], true );
    cswap(K[6],I[6],K[7],I[7], false);
    // k=4, j=2 (up by (i&4)==0)
    cswap(K[0],I[0],K[2],I[2], true );
    cswap(K[1],I[1],K[3],I[3], true );
    cswap(K[4],I[4],K[6],I[6], false);
    cswap(K[5],I[5],K[7],I[7], false);
    // k=4, j=1
    cswap(K[0],I[0],K[1],I[1], true );
    cswap(K[2],I[2],K[3],I[3], true );
    cswap(K[4],I[4],K[5],I[5], false);
    cswap(K[6],I[6],K[7],I[7], false);
    // k=8: up uniform per thread = ((b8 & 8) == 0)
    {
        const bool u8 = ((b8 & 8) == 0);
        cswap(K[0],I[0],K[4],I[4], u8); cswap(K[1],I[1],K[5],I[5], u8);
        cswap(K[2],I[2],K[6],I[6], u8); cswap(K[3],I[3],K[7],I[7], u8);
        cswap(K[0],I[0],K[2],I[2], u8); cswap(K[1],I[1],K[3],I[3], u8);
        cswap(K[4],I[4],K[6],I[6], u8); cswap(K[5],I[5],K[7],I[7], u8);
        cswap(K[0],I[0],K[1],I[1], u8); cswap(K[2],I[2],K[3],I[3], u8);
        cswap(K[4],I[4],K[5],I[5], u8); cswap(K[6],I[6],K[7],I[7], u8);
    }
    // store session
    {
        uint4 k0, k1, iv;
        k0.x=K[0]; k0.y=K[1]; k0.z=K[2]; k0.w=K[3];
        k1.x=K[4]; k1.y=K[5]; k1.z=K[6]; k1.w=K[7];
        iv.x=(unsigned int)I[0] | ((unsigned int)I[1]<<16);
        iv.y=(unsigned int)I[2] | ((unsigned int)I[3]<<16);
        iv.z=(unsigned int)I[4] | ((unsigned int)I[5]<<16);
        iv.w=(unsigned int)I[6] | ((unsigned int)I[7]<<16);
        *reinterpret_cast<uint4*>(&sh_key[b8])     = k0;
        *reinterpret_cast<uint4*>(&sh_key[b8 + 4]) = k1;
        *reinterpret_cast<uint4*>(&sh_idx[b8])     = iv;
    }
    __syncthreads();

    // ---- bitonic rounds k=16..2048: j>=8 via LDS (pair-indexed, all threads
    //      active), j=4,2,1 tail in registers ----
    for (int k = 16; k <= NSORT; k <<= 1) {
        for (int j = k >> 1; j >= 8; j >>= 1) {
            for (int p = tid; p < (NSORT >> 1); p += BLOCK) {
                const int i   = ((p & ~(j - 1)) << 1) | (p & (j - 1));
                const int ixj = i | j;
                const unsigned int ka = sh_key[i], kb = sh_key[ixj];
                const unsigned short ia = sh_idx[i], ib = sh_idx[ixj];
                const bool gt = (ka > kb) || (ka == kb && ia > ib);
                const bool up = ((i & k) == 0);
                if (gt == up) {
                    sh_key[i] = kb; sh_key[ixj] = ka;
                    sh_idx[i] = ib; sh_idx[ixj] = ia;
                }
            }
            __syncthreads();
        }
        // register tail: j = 4, 2, 1 (direction uniform within the 8-block)
        {
            const uint4 k0 = *reinterpret_cast<const uint4*>(&sh_key[b8]);
            const uint4 k1 = *reinterpret_cast<const uint4*>(&sh_key[b8 + 4]);
            const uint4 iv = *reinterpret_cast<const uint4*>(&sh_idx[b8]);
            K[0]=k0.x; K[1]=k0.y; K[2]=k0.z; K[3]=k0.w;
            K[4]=k1.x; K[5]=k1.y; K[6]=k1.z; K[7]=k1.w;
            I[0]=(unsigned short)(iv.x); I[1]=(unsigned short)(iv.x>>16);
            I[2]=(unsigned short)(iv.y); I[3]=(unsigned short)(iv.y>>16);
            I[4]=(unsigned short)(iv.z); I[5]=(unsigned short)(iv.z>>16);
            I[6]=(unsigned short)(iv.w); I[7]=(unsigned short)(iv.w>>16);
            const bool u8 = ((b8 & k) == 0);
            cswap(K[0],I[0],K[4],I[4], u8); cswap(K[1],I[1],K[5],I[5], u8);
            cswap(K[2],I[2],K[6],I[6], u8); cswap(K[3],I[3],K[7],I[7], u8);
            cswap(K[0],I[0],K[2],I[2], u8); cswap(K[1],I[1],K[3],I[3], u8);
            cswap(K[4],I[4],K[6],I[6], u8); cswap(K[5],I[5],K[7],I[7], u8);
            cswap(K[0],I[0],K[1],I[1], u8); cswap(K[2],I[2],K[3],I[3], u8);
            cswap(K[4],I[4],K[5],I[5], u8); cswap(K[6],I[6],K[7],I[7], u8);
            uint4 o0, o1, ov;
            o0.x=K[0]; o0.y=K[1]; o0.z=K[2]; o0.w=K[3];
            o1.x=K[4]; o1.y=K[5]; o1.z=K[6]; o1.w=K[7];
            ov.x=(unsigned int)I[0] | ((unsigned int)I[1]<<16);
            ov.y=(unsigned int)I[2] | ((unsigned int)I[3]<<16);
            ov.z=(unsigned int)I[4] | ((unsigned int)I[5]<<16);
            ov.w=(unsigned int)I[6] | ((unsigned int)I[7]<<16);
            *reinterpret_cast<uint4*>(&sh_key[b8])     = o0;
            *reinterpret_cast<uint4*>(&sh_key[b8 + 4]) = o1;
            *reinterpret_cast<uint4*>(&sh_idx[b8])     = ov;
        }
        __syncthreads();
    }

    // ---- zero edge weights (reuse key array as float bits) ----
    for (int e = tid; e < NE; e += BLOCK) sh_key[e] = 0u;   // 0.0f
    __syncthreads();

    // ---- single-wave chunked Kruskal (wave 0 only, no block barriers) ----
    // Register-maintained roots (r3-verified): each lane keeps its candidate's
    // CURRENT roots; after every wave-uniform commit of (rl -> rs) all lanes
    // apply {if (r == rl) r = rs} — mid-pass cycles detected in registers.
    // Merge body specialized by mode (see above).
    if (tid < 64) {
        const int lane = tid;
        for (int pass = 0; pass < NPASS; ++pass) {
            const int e = sh_idx[pass * CHUNK + lane];
            int a, bb; edge_nodes(e, a, bb);
            int ra = find_par(sh_parent, a);
            int rb = find_par(sh_parent, bb);
            ull m = __ballot(ra != rb);
            while (m) {
                const int i = (int)__builtin_ctzll(m);
                m &= m - 1;
                const unsigned int pack = (unsigned int)ra | ((unsigned int)rb << 10) | ((unsigned int)e << 20);
                const unsigned int pk = (unsigned int)__shfl((int)pack, i);
                const int ra_i = (int)(pk & 1023u);
                const int rb_i = (int)((pk >> 10) & 1023u);
                if (ra_i == rb_i) continue;            // became a cycle mid-pass
                const int se = (int)(pk >> 20);
                const unsigned int xa = sh_szto[ra_i], xb = sh_szto[rb_i];
                const int ta = (int)(xa >> 16), tb = (int)(xb >> 16);
                // survivor = larger component (weight symmetric; union by size;
                // representative choice does not affect component contents)
                const int big = ((xa & 0xFFFFu) > (xb & 0xFFFFu));
                const int rs = big ? ra_i : rb_i;
                const int rl = big ? rb_i : ra_i;
                int wv;
                if (mode == 0) {
                    // L==1 (pos sign): same == ta*tb -> wv = same
                    wv = ta * tb;
                } else if (mode == 1) {
                    const ull a0 = sh_cnt64[ra_i * 3];
                    const ull b0 = sh_cnt64[rb_i * 3];
                    const int same = dot16x4(a0, b0);
                    wv = sign ? same : (ta * tb - same);
                    if (lane == 0 && (ta + tb) > 0)
                        sh_cnt64[rs * 3] = a0 + b0;   // per-lane sums <= 1024: no carry
                } else {
                    const ull a0 = sh_cnt64[ra_i * 3 + 0];
                    const ull a1 = sh_cnt64[ra_i * 3 + 1];
                    const ull a2 = sh_cnt64[ra_i * 3 + 2];
                    const ull b0 = sh_cnt64[rb_i * 3 + 0];
                    const ull b1 = sh_cnt64[rb_i * 3 + 1];
                    const ull b2 = sh_cnt64[rb_i * 3 + 2];
                    const int same = dot16x4(a0, b0) + dot16x4(a1, b1) + dot16x4(a2, b2);
                    wv = sign ? same : (ta * tb - same);
                    if (lane == 0 && (ta + tb) > 0) {
                        sh_cnt64[rs * 3 + 0] = a0 + b0;
                        sh_cnt64[rs * 3 + 1] = a1 + b1;
                        sh_cnt64[rs * 3 + 2] = a2 + b2;
                    }
                }
                if (lane == 0) {
                    sh_key[se] = __float_as_uint((float)wv);
                    // size sum <= 2048, tot sum <= 2048 -> no field carry
                    sh_szto[rs] = xa + xb;
                    sh_parent[rl] = (unsigned short)rs;
                }
                // every lane tracks the merge in registers
                if (ra == rl) ra = rs;
                if (rb == rl) rb = rs;
            }
        }
    }
    __syncthreads();

    // ---- normalization sum (all weights integer-valued < 2^24: exact) ----
    {
        float part = 0.0f;
        for (int e = tid; e < NE; e += BLOCK) part += __uint_as_float(sh_key[e]);
        for (int off = 32; off > 0; off >>= 1) part += __shfl_down(part, off, 64);
        if ((tid & 63) == 0) sh_red[tid >> 6] = (double)part;
        __syncthreads();
        if (tid == 0) sh_sn = (float)(sh_red[0] + sh_red[1] + sh_red[2] + sh_red[3]);
        __syncthreads();
    }
    const float sn = sh_sn;

    // ---- per-node gather (reference add order) + conn contribution ----
    double acc = 0.0;
    for (int pix = tid; pix < NNODE; pix += BLOCK) {
        const int r = pix >> 5, c = pix & 31;
        float nw = 0.0f;
        // right edge
        if (c < 31) { const int e = r * 31 + c;
            float v = __uint_as_float(sh_key[e]); if (sn > 0.0f) v = v / sn;
            const float g = sh_t[pix] + sh_t[pix + 1];
            if (sign == 0) { if (g >= 3.0f) v = 0.0f; } else { if (g < 10.0f) v = 0.0f; }
            nw += v; }
        // left edge
        if (c > 0)  { const int e = r * 31 + c - 1;
            float v = __uint_as_float(sh_key[e]); if (sn > 0.0f) v = v / sn;
            const float g = sh_t[pix - 1] + sh_t[pix];
            if (sign == 0) { if (g >= 3.0f) v = 0.0f; } else { if (g < 10.0f) v = 0.0f; }
            nw += v; }
        // down edge
        if (r < 31) { const int e = NH + pix;
            float v = __uint_as_float(sh_key[e]); if (sn > 0.0f) v = v / sn;
            const float g = sh_t[pix] + sh_t[pix + 32];
            if (sign == 0) { if (g >= 3.0f) v = 0.0f; } else { if (g < 10.0f) v = 0.0f; }
            nw += v; }
        // up edge
        if (r > 0)  { const int e = NH + pix - 32;
            float v = __uint_as_float(sh_key[e]); if (sn > 0.0f) v = v / sn;
            const float g = sh_t[pix - 32] + sh_t[pix];
            if (sign == 0) { if (g >= 3.0f) v = 0.0f; } else { if (g < 10.0f) v = 0.0f; }
            nw += v; }
        const float p = sh_p[pix];
        float term;
        if (sign == 0) {
            term = (p * p) * nw;
        } else {
            const float d = 20.0f - p;
            term = (0.1f * (d * d)) * nw;
        }
        acc += (double)term;
    }
    for (int off = 32; off > 0; off >>= 1) acc += __shfl_down(acc, off, 64);
    if ((tid & 63) == 0) sh_red[tid >> 6] = acc;
    __syncthreads();
    if (tid == 0)
        atomicAdd(&acc_ws[1], sh_red[0] + sh_red[1] + sh_red[2] + sh_red[3]);

    } // !skip_all
}

__global__ __launch_bounds__(BLOCK) void mse_kernel(const float* __restrict__ pred,
                                                    const float* __restrict__ tgt,
                                                    double* __restrict__ acc_ws,
                                                    long n) {
    double acc = 0.0;
    for (long i = (long)blockIdx.x * BLOCK + threadIdx.x; i < n; i += (long)gridDim.x * BLOCK) {
        const float d = pred[i] - tgt[i];
        acc += (double)(d * d);
    }
    for (int off = 32; off > 0; off >>= 1) acc += __shfl_down(acc, off, 64);
    __shared__ double red[4];
    if ((threadIdx.x & 63) == 0) red[threadIdx.x >> 6] = acc;
    __syncthreads();
    if (threadIdx.x == 0)
        atomicAdd(&acc_ws[0], red[0] + red[1] + red[2] + red[3]);
}

__global__ void fin_kernel(const double* __restrict__ acc_ws, float* __restrict__ out, long n) {
    if (threadIdx.x == 0 && blockIdx.x == 0) {
        out[0] = (float)(acc_ws[0] / (double)n);
        out[1] = (float)(acc_ws[1] * (double)1e-4f);
    }
}

extern "C" void kernel_launch(void* const* d_in, const int* in_sizes, int n_in,
                              void* d_out, int out_size, void* d_ws, size_t ws_size,
                              hipStream_t stream) {
    const float* pred = (const float*)d_in[0];
    const float* tgt  = (const float*)d_in[1];
    float* out = (float*)d_out;
    double* acc = (double*)d_ws;

    const long n = (long)in_sizes[0];            // 4*1*128*128*128 = 8388608
    const int  B = (int)(n / 2097152);           // batches

    hipMemsetAsync(d_ws, 0, 2 * sizeof(double), stream);
    mse_kernel<<<1024, BLOCK, 0, stream>>>(pred, tgt, acc, n);
    // grid: 24 items x 4 windows x B batches x 2 signs
    conn_kernel<<<192 * B, BLOCK, 0, stream>>>(pred, tgt, acc, B);
    fin_kernel<<<1, 64, 0, stream>>>(acc, out, n);
}